// Round 11
// baseline (5723.018 us; speedup 1.0000x reference)
//
#include <hip/hip_runtime.h>
#include <hip/hip_bf16.h>

#define TT 512
#define BB 32
#define EE 256
#define UU 256
#define NG 1024   // 4*U

typedef unsigned int u32;
typedef unsigned long long u64;
typedef unsigned short u16;
typedef __attribute__((ext_vector_type(8))) short short8;   // 8 bf16 (4 VGPRs)
typedef __attribute__((ext_vector_type(4))) float f32x4;
typedef __attribute__((ext_vector_type(4))) u32 u32x4;

#define TAGMASK 0x0000FFFF0000FFFFull

__device__ __forceinline__ float bf2f(u16 u) { return __uint_as_float(((u32)u) << 16); }
__device__ __forceinline__ u16 f2bf(float f) {
    u32 x = __float_as_uint(f);
    u32 r = (x + 0x7fffu + ((x >> 16) & 1u)) >> 16;   // RNE
    return (u16)r;
}

// ---------------- Phase 1: xw2[dir][t'][ug][b][128] = (emb[tokens] @ Wk + bias), bf16 ----
// (r0 verbatim)
__launch_bounds__(256)
__global__ void xw_gemm(const int* __restrict__ tokens,
                        const float* __restrict__ emb,
                        const float* __restrict__ Wk_f, const float* __restrict__ b_f,
                        const float* __restrict__ Wk_b, const float* __restrict__ b_b,
                        u16* __restrict__ xw)
{
    const int dir = blockIdx.z;
    const float* Wk   = dir ? Wk_b : Wk_f;
    const float* bias = dir ? b_b  : b_f;
    const int bn = blockIdx.x;   // 8 tiles of 128 cols
    const int bm = blockIdx.y;   // 256 tiles of 64 rows
    const int tid = threadIdx.x;

    __shared__ __align__(16) float At[32][68];
    __shared__ __align__(16) float Bs[32][132];

    float acc[8][4];
#pragma unroll
    for (int i = 0; i < 8; i++)
#pragma unroll
        for (int j = 0; j < 4; j++) acc[i][j] = 0.f;

    const int tx = tid & 31;
    const int ty = tid >> 5;
    const int c0 = tx * 4;
    const int r0 = ty * 8;

    const int lr = tid >> 3;
    const int lk = (tid & 7) * 4;

    for (int k0 = 0; k0 < EE; k0 += 32) {
#pragma unroll
        for (int p = 0; p < 2; p++) {
            int r = lr + p * 32;
            int row = bm * 64 + r;
            int tok = tokens[row];
            const float4 v = *reinterpret_cast<const float4*>(&emb[(size_t)tok * EE + k0 + lk]);
            At[lk + 0][r] = v.x; At[lk + 1][r] = v.y; At[lk + 2][r] = v.z; At[lk + 3][r] = v.w;
        }
        {
            int ck = (tid & 31) * 4;
            int kk = tid >> 5;
#pragma unroll
            for (int p = 0; p < 4; p++) {
                int k = kk + p * 8;
                const float4 v = *reinterpret_cast<const float4*>(&Wk[(size_t)(k0 + k) * NG + bn * 128 + ck]);
                *reinterpret_cast<float4*>(&Bs[k][ck]) = v;
            }
        }
        __syncthreads();
#pragma unroll 8
        for (int k = 0; k < 32; k++) {
            float4 a0 = *reinterpret_cast<const float4*>(&At[k][r0]);
            float4 a1 = *reinterpret_cast<const float4*>(&At[k][r0 + 4]);
            float4 b0 = *reinterpret_cast<const float4*>(&Bs[k][c0]);
            float a[8] = {a0.x, a0.y, a0.z, a0.w, a1.x, a1.y, a1.z, a1.w};
            float b[4] = {b0.x, b0.y, b0.z, b0.w};
#pragma unroll
            for (int i = 0; i < 8; i++)
#pragma unroll
                for (int j = 0; j < 4; j++)
                    acc[i][j] = fmaf(a[i], b[j], acc[i][j]);
        }
        __syncthreads();
    }

    float4 bv = *reinterpret_cast<const float4*>(&bias[bn * 128 + c0]);
    float bias4[4] = {bv.x, bv.y, bv.z, bv.w};
    const int cbase = bn * 128 + c0;
    const int gate  = cbase >> 8;
    const int unitv = cbase & 255;
    const int ugx   = unitv >> 5;
    const int wcol  = gate * 32 + (unitv & 31);
#pragma unroll
    for (int i = 0; i < 8; i++) {
        int row = bm * 64 + r0 + i;
        int b = row >> 9;
        int t = row & 511;
        int t2 = dir ? (TT - 1 - t) : t;
        size_t base = ((((size_t)(dir * TT + t2)) * 8 + ugx) * BB + b) * 128 + wcol;
        ushort4 st;
        st.x = f2bf(acc[i][0] + bias4[0]);
        st.y = f2bf(acc[i][1] + bias4[1]);
        st.z = f2bf(acc[i][2] + bias4[2]);
        st.w = f2bf(acc[i][3] + bias4[3]);
        *reinterpret_cast<ushort4*>(&xw[base]) = st;
    }
}

__device__ __forceinline__ u64 ld_agent(const u64* p) {
    return __hip_atomic_load(p, __ATOMIC_RELAXED, __HIP_MEMORY_SCOPE_AGENT);
}

// ---------------- Phase 2: transposed recurrence, 8 WGs (4 per direction) -----------------
// Each WG owns 64 units; Wr slice (256 rows x 256 cols) in registers as the MFMA A-operand
// (z^T = Wr^T . h^T): D rows = units, D cols = batch -> all 4 gates land IN-LANE (no Zs
// LDS, no gate redistribution). Split-K: local kt slices MFMA'd before the poll check so
// the early-issued poll's HBM RT hides under them. Barriers are lgkmcnt-only (no vmcnt
// drain). Exchange protocol = r0's proven one: relaxed agent u64 tagged stores (tag=step),
// hgq[par][dir][b(32)][pair(128)] memset per launch, check-freshest poll + sleep escape.
// 4-party lockstep is deadlock-free: every WG stores gen s (end of step s-1) before
// polling gen s (top of step s).
__launch_bounds__(256, 1)
__global__ void lstm_rec(const int* __restrict__ tokens,
                         const u16* __restrict__ xw,     // [dir][t][ug][b][128]
                         const float* __restrict__ Wr_f,
                         const float* __restrict__ Wr_b,
                         u64* __restrict__ hgq,          // 2*2*32*128 u64 = 128 KB (memset 0)
                         float* __restrict__ out)
{
    const int wq  = blockIdx.x;     // 0..7
    const int dir = wq >> 2;
    const int w   = wq & 3;         // quarter: units [w*64, w*64+64)
    const int tid = threadIdx.x;    // 0..255
    const int wv  = tid >> 6;       // wave 0..3
    const int l   = tid & 63;

    __shared__ __align__(16) u32 HsW[2][32 * 128];   // h generation buffers, swizzled (32 KB)

    const float* Wr = dir ? Wr_b : Wr_f;

    // ---- Wr A-fragments (bf16), once: wfrag[kt][gate], cols = gate*256 + w*64 + wv*16 + (l&15)
    short8 wfrag[8][4];              // 128 VGPRs
    {
        const int col = w * 64 + wv * 16 + (l & 15);
#pragma unroll
        for (int kt = 0; kt < 8; kt++)
#pragma unroll
            for (int g = 0; g < 4; g++) {
                int k0 = kt * 32 + (l >> 4) * 8;
                short8 v;
#pragma unroll
                for (int j = 0; j < 8; j++)
                    v[j] = (short)f2bf(Wr[(size_t)(k0 + j) * NG + g * 256 + col]);
                wfrag[kt][g] = v;
            }
    }

    // cell mapping: lane owns units u = ubase + r (r=0..3), b = nb*16 + (l&15) (nb=0..1)
    const int ubase = w * 64 + wv * 16 + ((l >> 4) << 2);
    const int bl    = l & 15;
    const int ug    = ubase >> 5;          // xw row group
    const int uo    = ubase & 31;          // offset within 32-unit group
    const int lp0   = ubase >> 1;          // global h-pair base (pairs lp0, lp0+1)
    const int gl    = lp0 >> 2;            // local granule (in [w*8, w*8+8))
    const int slotb = lp0 & 3;             // in {0, 2}
    // poll mapping: thread covers b = tid&31, three remote granules
    const int bq = tid & 31;
    const int gq = tid >> 5;               // 0..7
    int gg3[3];
#pragma unroll
    for (int i = 0; i < 3; i++) { int gi = i * 8 + gq; gg3[i] = (gi < w * 8) ? gi : gi + 8; }

    float h_st[2][4], c_st[2][4];
#pragma unroll
    for (int nb = 0; nb < 2; nb++)
#pragma unroll
        for (int r = 0; r < 4; r++) { h_st[nb][r] = 0.f; c_st[nb][r] = 0.f; }

    const u16* xwD = xw + (size_t)dir * TT * 8 * BB * 128;
    u64 pxw[4][2];
    int ptok[2];
#pragma unroll
    for (int nb = 0; nb < 2; nb++) {
        int b = nb * 16 + bl;
        const u16* p = xwD + (((size_t)0 * 8 + ug) * BB + b) * 128 + uo;
#pragma unroll
        for (int g = 0; g < 4; g++) pxw[g][nb] = *reinterpret_cast<const u64*>(p + g * 32);
        ptok[nb] = tokens[b * TT + (dir ? (TT - 1) : 0)];
    }

    float* outs_h = out + (size_t)BB * TT * 512;
    float* outs_c = outs_h + (size_t)BB * 512;

    u64 qp[12];   // early-issued poll snapshot (3 granules x 4 pairs)

    for (int s = 0; s < TT; s++) {
        f32x4 acc[4][2];
#pragma unroll
        for (int g = 0; g < 4; g++)
#pragma unroll
            for (int nb = 0; nb < 2; nb++) acc[g][nb] = (f32x4){0.f, 0.f, 0.f, 0.f};

        if (s > 0) {
            u32* Hb = HsW[s & 1];
            // ---- LOCAL kt MFMA first (granules [w*8,+8): written pre-barrier#1 last step)
#pragma unroll
            for (int kk = 0; kk < 2; kk++) {
                int kt = w * 2 + kk;
#pragma unroll
                for (int nb = 0; nb < 2; nb++) {
                    int b = nb * 16 + bl;
                    int gk = kt * 4 + (l >> 4);
                    short8 af = *reinterpret_cast<const short8*>(
                        &Hb[b * 128 + ((gk ^ (b & 7)) << 2)]);
#pragma unroll
                    for (int g = 0; g < 4; g++)
                        acc[g][nb] = __builtin_amdgcn_mfma_f32_16x16x32_bf16(wfrag[kt][g], af, acc[g][nb], 0, 0, 0);
                }
            }
            // ---- poll remote h (gen s): check the early-issued snapshot; reload-freshest
            {
                const u64 tp = (u64)(u32)s | ((u64)(u32)s << 32);
                const u64* pol = hgq + ((size_t)((s & 1) * 2 + dir) * 32 + bq) * 128;
                int rounds = 0;
                for (;;) {
                    u64 bad = 0;
#pragma unroll
                    for (int i = 0; i < 12; i++) bad |= qp[i] ^ tp;
                    if (__all((bad & TAGMASK) == 0ull)) break;
                    if (++rounds > 2) __builtin_amdgcn_s_sleep(1);
#pragma unroll
                    for (int i = 0; i < 3; i++)
#pragma unroll
                        for (int j = 0; j < 4; j++)
                            qp[i * 4 + j] = ld_agent(pol + gg3[i] * 4 + j);
                }
                // unpack remote into HsW[s&1]
#pragma unroll
                for (int i = 0; i < 3; i++) {
                    u32x4 v4;
#pragma unroll
                    for (int j = 0; j < 4; j++) {
                        u64 q = qp[i * 4 + j];
                        v4[j] = (u32)((q >> 16) & 0xFFFFu) | ((u32)(q >> 48) << 16);
                    }
                    *reinterpret_cast<u32x4*>(&Hb[bq * 128 + ((gg3[i] ^ (bq & 7)) << 2)]) = v4;
                }
            }
            asm volatile("s_waitcnt lgkmcnt(0)" ::: "memory");
            __builtin_amdgcn_s_barrier();           // (#2) remote h visible; NO vmcnt drain
            // ---- REMOTE kt MFMA
#pragma unroll
            for (int kk = 0; kk < 6; kk++) {
                int kt = (kk < w * 2) ? kk : kk + 2;
#pragma unroll
                for (int nb = 0; nb < 2; nb++) {
                    int b = nb * 16 + bl;
                    int gk = kt * 4 + (l >> 4);
                    short8 af = *reinterpret_cast<const short8*>(
                        &Hb[b * 128 + ((gk ^ (b & 7)) << 2)]);
#pragma unroll
                    for (int g = 0; g < 4; g++)
                        acc[g][nb] = __builtin_amdgcn_mfma_f32_16x16x32_bf16(wfrag[kt][g], af, acc[g][nb], 0, 0, 0);
                }
            }
        }

        // ---- cell: 8 (u, b) per lane, all gates in-lane ----
        float h2[2][4], c2[2][4];
#pragma unroll
        for (int nb = 0; nb < 2; nb++) {
            const bool m = (ptok[nb] != 0);
#pragma unroll
            for (int r = 0; r < 4; r++) {
                float zi = acc[0][nb][r] + bf2f((u16)(pxw[0][nb] >> (16 * r)));
                float zf = acc[1][nb][r] + bf2f((u16)(pxw[1][nb] >> (16 * r)));
                float zg = acc[2][nb][r] + bf2f((u16)(pxw[2][nb] >> (16 * r)));
                float zo = acc[3][nb][r] + bf2f((u16)(pxw[3][nb] >> (16 * r)));
                float ii = 1.f / (1.f + __expf(-zi));
                float ff = 1.f / (1.f + __expf(-zf));
                float gg = fmaxf(zg, 0.f);
                float oo = 1.f / (1.f + __expf(-zo));
                float cn = ff * c_st[nb][r] + ii * gg;
                float hn = oo * fmaxf(cn, 0.f);
                h2[nb][r] = m ? hn : h_st[nb][r];
                c2[nb][r] = m ? cn : c_st[nb][r];
                h_st[nb][r] = h2[nb][r];
                c_st[nb][r] = c2[nb][r];
            }
        }

        if (s + 1 < TT) {
            // ---- h-store FIRST (critical path): tagged u64 pairs, relaxed agent (r0-proven)
            const u32 tagn = (u32)(s + 1);
            u64* st = hgq + ((size_t)(((s + 1) & 1) * 2 + dir) * 32) * 128;
#pragma unroll
            for (int nb = 0; nb < 2; nb++) {
                int b = nb * 16 + bl;
#pragma unroll
                for (int pr = 0; pr < 2; pr++) {
                    u32 qlo = ((u32)f2bf(h2[nb][2 * pr + 0]) << 16) | tagn;
                    u32 qhi = ((u32)f2bf(h2[nb][2 * pr + 1]) << 16) | tagn;
                    __hip_atomic_store(st + (size_t)b * 128 + lp0 + pr,
                                       (u64)qlo | ((u64)qhi << 32),
                                       __ATOMIC_RELAXED, __HIP_MEMORY_SCOPE_AGENT);
                }
            }
            // ---- local h into HsW[(s+1)&1] (pairs lp0, lp0+1 -> granule gl slots slotb..+1)
            u32* Hn = HsW[(s + 1) & 1];
#pragma unroll
            for (int nb = 0; nb < 2; nb++) {
                int b = nb * 16 + bl;
                u32 w0 = (u32)f2bf(h2[nb][0]) | ((u32)f2bf(h2[nb][1]) << 16);
                u32 w1 = (u32)f2bf(h2[nb][2]) | ((u32)f2bf(h2[nb][3]) << 16);
                *reinterpret_cast<u64*>(&Hn[b * 128 + ((gl ^ (b & 7)) << 2) + slotb]) =
                    (u64)w0 | ((u64)w1 << 32);
            }
            // ---- early-issue next poll round (checked after next step's local MFMA)
            const u64* pol2 = hgq + ((size_t)(((s + 1) & 1) * 2 + dir) * 32 + bq) * 128;
#pragma unroll
            for (int i = 0; i < 3; i++)
#pragma unroll
                for (int j = 0; j < 4; j++)
                    qp[i * 4 + j] = ld_agent(pol2 + gg3[i] * 4 + j);
        }

        // ---- out stores + finals (off critical path) ----
        const int tv = dir ? (TT - 1 - s) : s;
#pragma unroll
        for (int nb = 0; nb < 2; nb++) {
            int b = nb * 16 + bl;
            *reinterpret_cast<f32x4*>(&out[((size_t)b * TT + tv) * 512 + dir * UU + ubase]) =
                (f32x4){h2[nb][0], h2[nb][1], h2[nb][2], h2[nb][3]};
        }
        if (s == TT - 1) {
#pragma unroll
            for (int nb = 0; nb < 2; nb++) {
                int b = nb * 16 + bl;
                if (dir == 0) {
                    *reinterpret_cast<f32x4*>(&outs_h[b * 512 + ubase]) =
                        (f32x4){h2[nb][0], h2[nb][1], h2[nb][2], h2[nb][3]};
                    *reinterpret_cast<f32x4*>(&outs_c[b * 512 + ubase]) =
                        (f32x4){c2[nb][0], c2[nb][1], c2[nb][2], c2[nb][3]};
                } else {
                    // ref: state_h = concat(hf, cb); state_c = concat(cf, cb)
                    *reinterpret_cast<f32x4*>(&outs_h[b * 512 + UU + ubase]) =
                        (f32x4){c2[nb][0], c2[nb][1], c2[nb][2], c2[nb][3]};
                    *reinterpret_cast<f32x4*>(&outs_c[b * 512 + UU + ubase]) =
                        (f32x4){c2[nb][0], c2[nb][1], c2[nb][2], c2[nb][3]};
                }
            }
        }
        // ---- prefetch next xw/token; then barrier #1 (lgkm-only: local h visible) ----
        if (s + 1 < TT) {
#pragma unroll
            for (int nb = 0; nb < 2; nb++) {
                int b = nb * 16 + bl;
                const u16* p = xwD + (((size_t)(s + 1) * 8 + ug) * BB + b) * 128 + uo;
#pragma unroll
                for (int g = 0; g < 4; g++) pxw[g][nb] = *reinterpret_cast<const u64*>(p + g * 32);
                ptok[nb] = tokens[b * TT + (dir ? (TT - 2 - s) : (s + 1))];
            }
            asm volatile("s_waitcnt lgkmcnt(0)" ::: "memory");
            __builtin_amdgcn_s_barrier();           // (#1) NO vmcnt drain
        }
    }
}

extern "C" void kernel_launch(void* const* d_in, const int* in_sizes, int n_in,
                              void* d_out, int out_size, void* d_ws, size_t ws_size,
                              hipStream_t stream) {
    const int*   tokens = (const int*)d_in[0];
    const float* emb    = (const float*)d_in[1];
    const float* Wk_f   = (const float*)d_in[2];
    const float* Wr_f   = (const float*)d_in[3];
    const float* b_f    = (const float*)d_in[4];
    const float* Wk_b   = (const float*)d_in[5];
    const float* Wr_b   = (const float*)d_in[6];
    const float* b_b    = (const float*)d_in[7];
    float* out = (float*)d_out;

    char* ws = (char*)d_ws;
    u16* xw  = (u16*)ws;                       // 67,108,864 B
    u64* hgq = (u64*)(ws + 67108864);          // 131,072 B: [par][dir][b][pair] tagged u64

    (void)hipMemsetAsync(hgq, 0, 131072, stream);
    dim3 g1(8, 256, 2);
    xw_gemm<<<g1, 256, 0, stream>>>(tokens, emb, Wk_f, b_f, Wk_b, b_b, xw);
    lstm_rec<<<8, 256, 0, stream>>>(tokens, xw, Wr_f, Wr_b, hgq, out);
}